// Round 5
// baseline (811.277 us; speedup 1.0000x reference)
//
#include <hip/hip_runtime.h>
#include <hip/hip_bf16.h>
#include <stdint.h>

typedef unsigned short u16;
typedef _Float16 f16;
typedef short vs8 __attribute__((ext_vector_type(8)));   // 8 x bf16 bits (MFMA A/B frag)
typedef float vf4 __attribute__((ext_vector_type(4)));   // MFMA C/D frag
typedef _Float16 vh2 __attribute__((ext_vector_type(2)));
typedef _Float16 vh4 __attribute__((ext_vector_type(4)));
typedef _Float16 vh8 __attribute__((ext_vector_type(8)));

// Problem constants: B=4 T=2048 E=256 H=8 HD=32 FE=4 L=4

__device__ __forceinline__ void gload16(const u16* g, u16* l) {
  __builtin_amdgcn_global_load_lds((const __attribute__((address_space(1))) void*)g,
                                   (__attribute__((address_space(3))) void*)l,
                                   16, 0, 0);
}

// ---------------- Fourier PE + bf16 cast ----------------
__global__ void pe_kernel(const float* __restrict__ x, float* __restrict__ X,
                          __hip_bfloat16* __restrict__ Xb) {
  int row = blockIdx.x;            // b*2048 + t
  int e = threadIdx.x;             // 0..255
  int t = row & 2047;
  int f = (e < 128) ? e : (e - 128);
  float freq = powf(10000.0f, -(float)f * (1.0f / 128.0f));
  float arg = (float)t * freq;
  float pe = (e < 128) ? sinf(arg) : cosf(arg);
  size_t idx = (size_t)row * 256 + e;
  float v = x[idx] + pe;
  X[idx] = v;
  Xb[idx] = __float2bfloat16(v);
}

// ---------------- weight transpose + cast: in[L][K][N] f32 -> out[L][N][K] bf16 ----------------
__global__ void transpose_cast(const float* __restrict__ in, __hip_bfloat16* __restrict__ out,
                               int K, int N) {
  __shared__ float tile[32][33];
  int layer = blockIdx.z;
  int k0 = blockIdx.x * 32, n0 = blockIdx.y * 32;
  const float* ip = in + (size_t)layer * K * N;
  __hip_bfloat16* op = out + (size_t)layer * N * K;
  int tx = threadIdx.x, ty = threadIdx.y;   // (32,8)
#pragma unroll
  for (int r = 0; r < 4; ++r) {
    int k = ty + r * 8;
    tile[k][tx] = ip[(size_t)(k0 + k) * N + (n0 + tx)];
  }
  __syncthreads();
#pragma unroll
  for (int r = 0; r < 4; ++r) {
    int n = ty + r * 8;
    op[(size_t)(n0 + n) * K + (k0 + tx)] = __float2bfloat16(tile[tx][n]);
  }
}

// ---------------- bf16 MFMA GEMM 128x128 (ff1): C = A@W + bias + relu -> bf16 ----------------
__global__ __launch_bounds__(256, 2) void gemm_bf16(
    const u16* __restrict__ A, const u16* __restrict__ Bt,
    const float* __restrict__ bias, __hip_bfloat16* __restrict__ outB,
    int M, int N, int K) {
  __shared__ u16 As[128 * 32];
  __shared__ u16 Bs[128 * 32];
  int tid = threadIdx.x;
  int wave = tid >> 6, lane = tid & 63;
  int wm = wave & 1, wn = wave >> 1;              // 2x2 waves of 64x64
  int m0 = blockIdx.y * 128, n0 = blockIdx.x * 128;
  int lr = lane & 15, lq = lane >> 4;

  vf4 acc[4][4];
#pragma unroll
  for (int i = 0; i < 4; ++i)
#pragma unroll
    for (int j = 0; j < 4; ++j) {
      acc[i][j][0] = 0.f; acc[i][j][1] = 0.f; acc[i][j][2] = 0.f; acc[i][j][3] = 0.f;
    }

  int srow = wave * 16 + (lane >> 2);
  int scol = (lane & 3) * 8;
  const u16* ag = A + (size_t)(m0 + srow) * K + scol;
  const u16* bg = Bt + (size_t)(n0 + srow) * K + scol;
  u16* al = As + srow * 32 + scol;
  u16* bl = Bs + srow * 32 + scol;
  const size_t rstride = (size_t)64 * K;

  for (int k0 = 0; k0 < K; k0 += 32) {
    gload16(ag + k0, al);
    gload16(ag + k0 + rstride, al + 64 * 32);
    gload16(bg + k0, bl);
    gload16(bg + k0 + rstride, bl + 64 * 32);
    __syncthreads();
    vs8 av[4], bv[4];
#pragma unroll
    for (int i = 0; i < 4; ++i)
      av[i] = *(const vs8*)&As[(wm * 64 + i * 16 + lr) * 32 + lq * 8];
#pragma unroll
    for (int j = 0; j < 4; ++j)
      bv[j] = *(const vs8*)&Bs[(wn * 64 + j * 16 + lr) * 32 + lq * 8];
#pragma unroll
    for (int i = 0; i < 4; ++i)
#pragma unroll
      for (int j = 0; j < 4; ++j)
        acc[i][j] = __builtin_amdgcn_mfma_f32_16x16x32_bf16(av[i], bv[j], acc[i][j], 0, 0, 0);
    __syncthreads();
  }

#pragma unroll
  for (int i = 0; i < 4; ++i) {
    int row0 = m0 + wm * 64 + i * 16 + lq * 4;
#pragma unroll
    for (int j = 0; j < 4; ++j) {
      int col = n0 + wn * 64 + j * 16 + lr;
      float bb = bias[col];
#pragma unroll
      for (int r = 0; r < 4; ++r) {
        size_t idx = (size_t)(row0 + r) * N + col;
        outB[idx] = __float2bfloat16(fmaxf(acc[i][j][r] + bb, 0.0f));
      }
    }
  }
}

// ---------------- bf16 MFMA GEMM 64x128 (qkv): C = A@W + bias -> f16 ----------------
// Grid (N/128, M/64) = (6,128) = 768 blocks -> 3/CU balanced.
__global__ __launch_bounds__(256, 2) void gemm_qkv(
    const u16* __restrict__ A, const u16* __restrict__ Bt,
    const float* __restrict__ bias, f16* __restrict__ outH,
    int M, int N, int K) {
  __shared__ u16 As[64 * 32];
  __shared__ u16 Bs[128 * 32];
  int tid = threadIdx.x;
  int wave = tid >> 6, lane = tid & 63;
  int wm = wave & 1, wn = wave >> 1;              // wave = 32 rows x 64 cols
  int m0 = blockIdx.y * 64, n0 = blockIdx.x * 128;
  int lr = lane & 15, lq = lane >> 4;

  vf4 acc[2][4];
#pragma unroll
  for (int i = 0; i < 2; ++i)
#pragma unroll
    for (int j = 0; j < 4; ++j) { acc[i][j][0]=0.f; acc[i][j][1]=0.f; acc[i][j][2]=0.f; acc[i][j][3]=0.f; }

  int sr = tid >> 2, sc = (tid & 3) * 8;          // 64 rows x 64B, lane-linear per wave
  const u16* ag = A + (size_t)(m0 + sr) * K + sc;
  const u16* bg = Bt + (size_t)(n0 + sr) * K + sc;
  u16* al = As + sr * 32 + sc;
  u16* bl = Bs + sr * 32 + sc;

  for (int k0 = 0; k0 < K; k0 += 32) {
    gload16(ag + k0, al);
    gload16(bg + k0, bl);
    gload16(bg + k0 + (size_t)64 * K, bl + 64 * 32);
    __syncthreads();
    vs8 av[2], bv[4];
#pragma unroll
    for (int i = 0; i < 2; ++i)
      av[i] = *(const vs8*)&As[(wm * 32 + i * 16 + lr) * 32 + lq * 8];
#pragma unroll
    for (int j = 0; j < 4; ++j)
      bv[j] = *(const vs8*)&Bs[(wn * 64 + j * 16 + lr) * 32 + lq * 8];
#pragma unroll
    for (int i = 0; i < 2; ++i)
#pragma unroll
      for (int j = 0; j < 4; ++j)
        acc[i][j] = __builtin_amdgcn_mfma_f32_16x16x32_bf16(av[i], bv[j], acc[i][j], 0, 0, 0);
    __syncthreads();
  }

#pragma unroll
  for (int i = 0; i < 2; ++i) {
    int row0 = m0 + wm * 32 + i * 16 + lq * 4;
#pragma unroll
    for (int j = 0; j < 4; ++j) {
      int col = n0 + wn * 64 + j * 16 + lr;
      float bb = bias[col];
#pragma unroll
      for (int r = 0; r < 4; ++r)
        outH[(size_t)(row0 + r) * N + col] = (f16)(acc[i][j][r] + bb);
    }
  }
}

// ---------------- fused GEMM (N=256) + bias + residual + LayerNorm, 32-row tiles ----------------
// Grid = M/32 = 256 blocks (full GPU). Wave = 16 rows x 128 cols.
__global__ __launch_bounds__(256, 2) void gemm_ln(
    const u16* __restrict__ A, const u16* __restrict__ Bt,
    const float* __restrict__ bias, const float* __restrict__ res,
    const float* __restrict__ gam, const float* __restrict__ bet,
    float* __restrict__ outF, __hip_bfloat16* __restrict__ outB, int K) {
  __shared__ u16 As[32 * 32];
  __shared__ u16 Bs[256 * 32];
  __shared__ float ps[2][32], ps2[2][32], mur[32], rsr[32];
  int tid = threadIdx.x;
  int wave = tid >> 6, lane = tid & 63;
  int wm = wave & 1, wn = wave >> 1;
  int lr = lane & 15, lq = lane >> 4;
  int m0 = blockIdx.x * 32;

  vf4 acc[8];
#pragma unroll
  for (int j = 0; j < 8; ++j) { acc[j][0]=0.f; acc[j][1]=0.f; acc[j][2]=0.f; acc[j][3]=0.f; }

  int sr = tid >> 2, sc = (tid & 3) * 8;
  const u16* ag = A + (size_t)(m0 + sr) * K + sc;   // valid for tid<128 (rows 0..31)
  const u16* bg = Bt + (size_t)sr * K + sc;         // 256 rows: 4 rounds
  u16* al = As + sr * 32 + sc;
  u16* bl = Bs + sr * 32 + sc;

  for (int k0 = 0; k0 < K; k0 += 32) {
    if (tid < 128) gload16(ag + k0, al);
#pragma unroll
    for (int r = 0; r < 4; ++r)
      gload16(bg + k0 + (size_t)64 * r * K, bl + 64 * r * 32);
    __syncthreads();
    vs8 av, bv[8];
    av = *(const vs8*)&As[(wm * 16 + lr) * 32 + lq * 8];
#pragma unroll
    for (int j = 0; j < 8; ++j)
      bv[j] = *(const vs8*)&Bs[(wn * 128 + j * 16 + lr) * 32 + lq * 8];
#pragma unroll
    for (int j = 0; j < 8; ++j)
      acc[j] = __builtin_amdgcn_mfma_f32_16x16x32_bf16(av, bv[j], acc[j], 0, 0, 0);
    __syncthreads();
  }

  // v = acc + bias + residual; per-row partials
  float sum_[4], sq_[4];
#pragma unroll
  for (int r = 0; r < 4; ++r) { sum_[r] = 0.f; sq_[r] = 0.f; }
#pragma unroll
  for (int j = 0; j < 8; ++j) {
    int col = wn * 128 + j * 16 + lr;
    float bb = bias[col];
#pragma unroll
    for (int r = 0; r < 4; ++r) {
      int row = m0 + wm * 16 + lq * 4 + r;
      float v = acc[j][r] + bb + res[(size_t)row * 256 + col];
      acc[j][r] = v;
      sum_[r] += v;
      sq_[r] += v * v;
    }
  }
#pragma unroll
  for (int r = 0; r < 4; ++r) {
#pragma unroll
    for (int m = 1; m <= 8; m <<= 1) {
      sum_[r] += __shfl_xor(sum_[r], m);
      sq_[r]  += __shfl_xor(sq_[r], m);
    }
  }
  if (lr == 0) {
#pragma unroll
    for (int r = 0; r < 4; ++r) {
      int rl = wm * 16 + lq * 4 + r;
      ps[wn][rl] = sum_[r];
      ps2[wn][rl] = sq_[r];
    }
  }
  __syncthreads();
  if (tid < 32) {
    float s = ps[0][tid] + ps[1][tid];
    float s2 = ps2[0][tid] + ps2[1][tid];
    float mu = s * (1.0f / 256.0f);
    float var = s2 * (1.0f / 256.0f) - mu * mu;
    mur[tid] = mu;
    rsr[tid] = rsqrtf(var + 1e-5f);
  }
  __syncthreads();
#pragma unroll
  for (int r = 0; r < 4; ++r) {
    int rl = wm * 16 + lq * 4 + r;
    float mu = mur[rl], rs = rsr[rl];
    int row = m0 + rl;
#pragma unroll
    for (int j = 0; j < 8; ++j) {
      int col = wn * 128 + j * 16 + lr;
      float o = (acc[j][r] - mu) * rs * gam[col] + bet[col];
      size_t idx = (size_t)row * 256 + col;
      outF[idx] = o;
      outB[idx] = __float2bfloat16(o);
    }
  }
}

// ---------------- MFMA flash attention v3 ----------------
// Changes vs R4: (1) XCD-pinned swizzle: 1D grid 1024, xcd=id&7 owns 4 (b,h) groups ->
// K/V L2-resident per XCD. (2) Ks padded to 36 f16/row (conflict-free ds_read_b128; VGPR
// staging since global_load_lds needs lane-linear dest). (3) VTs pad 70 (<=2-way = free).
// (4) Register prefetch of chunk c+1 over compute of chunk c.
__global__ __launch_bounds__(512, 6) void attn_mfma(const f16* __restrict__ qkv,
                                                    __hip_bfloat16* __restrict__ out) {
  __shared__ __align__(16) u16 lds[18176];    // 36352 B: Ks 256*36 | VTs 4*32*70
  f16* Ks = (f16*)lds;                        // [256][36]  (strip p at rows p*64)
  f16* VTs = (f16*)lds + 9216;                // [4][32][70]
  float* Om = (float*)lds;                    // merge overlay [2][3][32][32] f32 (24576 B)
  float* lm = (float*)(lds + 12288);          // [2][3][32] f32 at byte 24576

  int tid = threadIdx.x;
  int wave = tid >> 6, lane = tid & 63;
  int lr = lane & 15, quad = lane >> 4;
  int qh = wave & 1, p = wave >> 1;

  // XCD-pinning decode (round-robin heuristic: xcd = dispatch id % 8)
  int Lid = blockIdx.x;
  int xcd = Lid & 7, slot = Lid >> 3;
  int grp = xcd + 8 * (slot >> 5);            // (b,h) group 0..31
  int qt = slot & 31;
  int b = grp >> 3, h = grp & 7;
  int q0 = qt * 64;
  int rowbase = b * 2048;
  const f16* base_bh = qkv + (size_t)rowbase * 768 + h * 96;

  // Q B-frags, pre-scaled by (1/sqrt(32))*log2(e)
  vh8 qf[2];
#pragma unroll
  for (int nt = 0; nt < 2; ++nt) {
    int qr = q0 + qh * 32 + nt * 16 + lr;
    vh8 t = *(const vh8*)(base_bh + (size_t)qr * 768 + quad * 8);
#pragma unroll
    for (int j = 0; j < 8; ++j) t[j] = t[j] * (f16)0.25508682f;
    qf[nt] = t;
  }

  vf4 O[2][2], lO[2];
#pragma unroll
  for (int a = 0; a < 2; ++a) {
    lO[a][0]=0.f; lO[a][1]=0.f; lO[a][2]=0.f; lO[a][3]=0.f;
#pragma unroll
    for (int d = 0; d < 2; ++d) { O[a][d][0]=0.f; O[a][d][1]=0.f; O[a][d][2]=0.f; O[a][d][3]=0.f; }
  }

  // staging maps (512 threads)
  int lrowK = tid >> 2;                // 0..127 (pair row lrowK+128)
  int colK = (tid & 3) * 8;
  int rV = tid >> 2;
  int d4V = (tid & 3) * 8;
  int pV = rV >> 5;
  int kvlV = (rV * 2) & 63;
  u16* kdst0 = (u16*)&Ks[lrowK * 36 + colK];
  u16* kdst1 = (u16*)&Ks[(lrowK + 128) * 36 + colK];
  f16* vdst = &VTs[(pV * 32 + d4V) * 70 + kvlV];

  const f16* kg0 = base_bh + (size_t)((lrowK >> 6) * 512 + (lrowK & 63)) * 768 + 32 + colK;
  const f16* kg1 = base_bh + (size_t)((lrowK >> 6) * 512 + 1024 + (lrowK & 63)) * 768 + 32 + colK;
  const f16* vg  = base_bh + (size_t)(pV * 512 + kvlV) * 768 + 64 + d4V;

  // prefetch chunk 0
  vh8 kr0 = *(const vh8*)kg0, kr1 = *(const vh8*)kg1;
  vh8 vr0 = *(const vh8*)vg,  vr1 = *(const vh8*)(vg + 768);
  kg0 += 64 * 768; kg1 += 64 * 768; vg += 64 * 768;

  const vf4 z4 = {0.f, 0.f, 0.f, 0.f};
  const vh4 onesh = {(f16)1.0f, (f16)1.0f, (f16)1.0f, (f16)1.0f};

  for (int c = 0; c < 8; ++c) {
    __syncthreads();                   // prev-chunk readers done
    *(vh8*)kdst0 = kr0;
    *(vh8*)kdst1 = kr1;
#pragma unroll
    for (int i = 0; i < 8; ++i) {
      vh2 pr; pr[0] = vr0[i]; pr[1] = vr1[i];
      *(vh2*)(vdst + i * 70) = pr;
    }
    __syncthreads();
    if (c < 7) {                       // prefetch next chunk into regs (overlaps compute)
      kr0 = *(const vh8*)kg0; kr1 = *(const vh8*)kg1;
      vr0 = *(const vh8*)vg;  vr1 = *(const vh8*)(vg + 768);
      kg0 += 64 * 768; kg1 += 64 * 768; vg += 64 * 768;
    }

#pragma unroll
    for (int t16 = 0; t16 < 4; ++t16) {
      vh8 ak = *(const vh8*)&Ks[(p * 64 + t16 * 16 + lr) * 36 + quad * 8];
      vf4 s0 = __builtin_amdgcn_mfma_f32_16x16x32_f16(ak, qf[0], z4, 0, 0, 0);
      vf4 s1 = __builtin_amdgcn_mfma_f32_16x16x32_f16(ak, qf[1], z4, 0, 0, 0);
      vh4 p0, p1;
#pragma unroll
      for (int i = 0; i < 4; ++i) {
        p0[i] = (f16)exp2f(s0[i]);
        p1[i] = (f16)exp2f(s1[i]);
      }
      vh4 vf0 = *(const vh4*)&VTs[(p * 32 + 0 * 16 + lr) * 70 + t16 * 16 + quad * 4];
      vh4 vf1 = *(const vh4*)&VTs[(p * 32 + 1 * 16 + lr) * 70 + t16 * 16 + quad * 4];
      O[0][0] = __builtin_amdgcn_mfma_f32_16x16x16f16(p0, vf0, O[0][0], 0, 0, 0);
      O[0][1] = __builtin_amdgcn_mfma_f32_16x16x16f16(p0, vf1, O[0][1], 0, 0, 0);
      O[1][0] = __builtin_amdgcn_mfma_f32_16x16x16f16(p1, vf0, O[1][0], 0, 0, 0);
      O[1][1] = __builtin_amdgcn_mfma_f32_16x16x16f16(p1, vf1, O[1][1], 0, 0, 0);
      lO[0] = __builtin_amdgcn_mfma_f32_16x16x16f16(p0, onesh, lO[0], 0, 0, 0);
      lO[1] = __builtin_amdgcn_mfma_f32_16x16x16f16(p1, onesh, lO[1], 0, 0, 0);
    }
  }

  // merge kv-quarters through LDS
  __syncthreads();
  if (p > 0) {
    int pp = p - 1;
#pragma unroll
    for (int nt = 0; nt < 2; ++nt)
#pragma unroll
      for (int r = 0; r < 4; ++r) {
        int ql_ = nt * 16 + quad * 4 + r;
        float* orow = &Om[((qh * 3 + pp) * 32 + ql_) * 32];
#pragma unroll
        for (int dt = 0; dt < 2; ++dt) orow[dt * 16 + lr] = O[nt][dt][r];
        if (lr == 0) lm[(qh * 3 + pp) * 32 + ql_] = lO[nt][r];
      }
  }
  __syncthreads();
  if (p == 0) {
#pragma unroll
    for (int nt = 0; nt < 2; ++nt)
#pragma unroll
      for (int r = 0; r < 4; ++r) {
        int ql_ = nt * 16 + quad * 4 + r;
        float l = lO[nt][r] + lm[(qh * 3 + 0) * 32 + ql_]
                            + lm[(qh * 3 + 1) * 32 + ql_]
                            + lm[(qh * 3 + 2) * 32 + ql_];
        float inv = 1.0f / l;
        int row = rowbase + q0 + qh * 32 + ql_;
#pragma unroll
        for (int dt = 0; dt < 2; ++dt) {
          float o = O[nt][dt][r]
                  + Om[((qh * 3 + 0) * 32 + ql_) * 32 + dt * 16 + lr]
                  + Om[((qh * 3 + 1) * 32 + ql_) * 32 + dt * 16 + lr]
                  + Om[((qh * 3 + 2) * 32 + ql_) * 32 + dt * 16 + lr];
          out[(size_t)row * 256 + h * 32 + dt * 16 + lr] = __float2bfloat16(o * inv);
        }
      }
  }
}

// ---------------- driver ----------------
extern "C" void kernel_launch(void* const* d_in, const int* in_sizes, int n_in,
                              void* d_out, int out_size, void* d_ws, size_t ws_size,
                              hipStream_t stream) {
  (void)in_sizes; (void)n_in; (void)out_size; (void)ws_size;
  const float* x     = (const float*)d_in[0];
  const float* qkv_b = (const float*)d_in[2];
  const float* out_b = (const float*)d_in[4];
  const float* ff1_b = (const float*)d_in[6];
  const float* ff2_b = (const float*)d_in[8];
  const float* ln1_g = (const float*)d_in[9];
  const float* ln1_b = (const float*)d_in[10];
  const float* ln2_g = (const float*)d_in[11];
  const float* ln2_b = (const float*)d_in[12];

  // ws layout (bytes); total = 44,040,192
  char* ws = (char*)d_ws;
  float*          X     = (float*)(ws + 0);                    // 8192x256 f32
  __hip_bfloat16* Xb    = (__hip_bfloat16*)(ws + 8388608);     // bf16 x
  __hip_bfloat16* attnB = (__hip_bfloat16*)(ws + 20971520);    // attn out bf16 (4 MB)
  f16*            qkvH  = (f16*)(ws + 25165824);               // 8192x768 f16 (12.6 MB)
  __hip_bfloat16* hB    = (__hip_bfloat16*)(ws + 20971520);    // ff1 out bf16 (16.8 MB) overlaps attnB+qkvH
  u16* qkvwT = (u16*)(ws + 37748736);  // [L][768][256] bf16
  u16* outwT = (u16*)(ws + 39321600);  // [L][256][256]
  u16* ff1wT = (u16*)(ws + 39845888);  // [L][1024][256]
  u16* ff2wT = (u16*)(ws + 41943040);  // [L][256][1024]  ends 44,040,192

  pe_kernel<<<8192, 256, 0, stream>>>(x, X, Xb);
  transpose_cast<<<dim3(8, 24, 4), dim3(32, 8), 0, stream>>>((const float*)d_in[1], (__hip_bfloat16*)qkvwT, 256, 768);
  transpose_cast<<<dim3(8, 8, 4),  dim3(32, 8), 0, stream>>>((const float*)d_in[3], (__hip_bfloat16*)outwT, 256, 256);
  transpose_cast<<<dim3(8, 32, 4), dim3(32, 8), 0, stream>>>((const float*)d_in[5], (__hip_bfloat16*)ff1wT, 256, 1024);
  transpose_cast<<<dim3(32, 8, 4), dim3(32, 8), 0, stream>>>((const float*)d_in[7], (__hip_bfloat16*)ff2wT, 1024, 256);

  for (int l = 0; l < 4; ++l) {
    // qkv = x @ qkv_w + b -> f16   (64x128 tiles, 768 blocks balanced)
    gemm_qkv<<<dim3(6, 128), 256, 0, stream>>>((const u16*)Xb, qkvwT + (size_t)l * 768 * 256,
        qkv_b + l * 768, qkvH, 8192, 768, 256);
    // attn (XCD-pinned 1D grid)
    attn_mfma<<<1024, 512, 0, stream>>>(qkvH, attnB);
    // X = LN1(attn @ out_w + b + X); Xb = bf16(X)
    gemm_ln<<<256, 256, 0, stream>>>((const u16*)attnB, outwT + (size_t)l * 256 * 256,
        out_b + l * 256, X, ln1_g + l * 256, ln1_b + l * 256, X, Xb, 256);
    // h = relu(x @ ff1_w + b) -> bf16
    gemm_bf16<<<dim3(8, 64), 256, 0, stream>>>((const u16*)Xb, ff1wT + (size_t)l * 1024 * 256,
        ff1_b + l * 1024, hB, 8192, 1024, 256);
    // X/out = LN2(h @ ff2_w + b + X); Xb = bf16(.)
    float* lnout = (l == 3) ? (float*)d_out : X;
    gemm_ln<<<256, 256, 0, stream>>>((const u16*)hB, ff2wT + (size_t)l * 256 * 1024,
        ff2_b + l * 256, X, ln2_g + l * 256, ln2_b + l * 256, lnout, Xb, 1024);
  }
}

// Round 6
// 577.511 us; speedup vs baseline: 1.4048x; 1.4048x over previous
//
#include <hip/hip_runtime.h>
#include <hip/hip_bf16.h>
#include <stdint.h>

typedef unsigned short u16;
typedef _Float16 f16;
typedef short vs8 __attribute__((ext_vector_type(8)));   // 8 x bf16 bits (MFMA A/B frag)
typedef float vf4 __attribute__((ext_vector_type(4)));   // MFMA C/D frag
typedef _Float16 vh2 __attribute__((ext_vector_type(2)));
typedef _Float16 vh4 __attribute__((ext_vector_type(4)));
typedef _Float16 vh8 __attribute__((ext_vector_type(8)));

// Problem constants: B=4 T=2048 E=256 H=8 HD=32 FE=4 L=4

__device__ __forceinline__ void gload16(const u16* g, u16* l) {
  __builtin_amdgcn_global_load_lds((const __attribute__((address_space(1))) void*)g,
                                   (__attribute__((address_space(3))) void*)l,
                                   16, 0, 0);
}

// ---------------- Fourier PE + bf16 cast ----------------
__global__ void pe_kernel(const float* __restrict__ x, float* __restrict__ X,
                          __hip_bfloat16* __restrict__ Xb) {
  int row = blockIdx.x;            // b*2048 + t
  int e = threadIdx.x;             // 0..255
  int t = row & 2047;
  int f = (e < 128) ? e : (e - 128);
  float freq = powf(10000.0f, -(float)f * (1.0f / 128.0f));
  float arg = (float)t * freq;
  float pe = (e < 128) ? sinf(arg) : cosf(arg);
  size_t idx = (size_t)row * 256 + e;
  float v = x[idx] + pe;
  X[idx] = v;
  Xb[idx] = __float2bfloat16(v);
}

// ---------------- weight transpose + cast: in[L][K][N] f32 -> out[L][N][K] bf16 ----------------
__global__ void transpose_cast(const float* __restrict__ in, __hip_bfloat16* __restrict__ out,
                               int K, int N) {
  __shared__ float tile[32][33];
  int layer = blockIdx.z;
  int k0 = blockIdx.x * 32, n0 = blockIdx.y * 32;
  const float* ip = in + (size_t)layer * K * N;
  __hip_bfloat16* op = out + (size_t)layer * N * K;
  int tx = threadIdx.x, ty = threadIdx.y;   // (32,8)
#pragma unroll
  for (int r = 0; r < 4; ++r) {
    int k = ty + r * 8;
    tile[k][tx] = ip[(size_t)(k0 + k) * N + (n0 + tx)];
  }
  __syncthreads();
#pragma unroll
  for (int r = 0; r < 4; ++r) {
    int n = ty + r * 8;
    op[(size_t)(n0 + n) * K + (k0 + tx)] = __float2bfloat16(tile[tx][n]);
  }
}

// ---------------- bf16 MFMA GEMM 128x128 (ff1): C = A@W + bias + relu -> bf16 ----------------
__global__ __launch_bounds__(256, 2) void gemm_bf16(
    const u16* __restrict__ A, const u16* __restrict__ Bt,
    const float* __restrict__ bias, __hip_bfloat16* __restrict__ outB,
    int M, int N, int K) {
  __shared__ u16 As[128 * 32];
  __shared__ u16 Bs[128 * 32];
  int tid = threadIdx.x;
  int wave = tid >> 6, lane = tid & 63;
  int wm = wave & 1, wn = wave >> 1;              // 2x2 waves of 64x64
  int m0 = blockIdx.y * 128, n0 = blockIdx.x * 128;
  int lr = lane & 15, lq = lane >> 4;

  vf4 acc[4][4];
#pragma unroll
  for (int i = 0; i < 4; ++i)
#pragma unroll
    for (int j = 0; j < 4; ++j) {
      acc[i][j][0] = 0.f; acc[i][j][1] = 0.f; acc[i][j][2] = 0.f; acc[i][j][3] = 0.f;
    }

  int srow = wave * 16 + (lane >> 2);
  int scol = (lane & 3) * 8;
  const u16* ag = A + (size_t)(m0 + srow) * K + scol;
  const u16* bg = Bt + (size_t)(n0 + srow) * K + scol;
  u16* al = As + srow * 32 + scol;
  u16* bl = Bs + srow * 32 + scol;
  const size_t rstride = (size_t)64 * K;

  for (int k0 = 0; k0 < K; k0 += 32) {
    gload16(ag + k0, al);
    gload16(ag + k0 + rstride, al + 64 * 32);
    gload16(bg + k0, bl);
    gload16(bg + k0 + rstride, bl + 64 * 32);
    __syncthreads();
    vs8 av[4], bv[4];
#pragma unroll
    for (int i = 0; i < 4; ++i)
      av[i] = *(const vs8*)&As[(wm * 64 + i * 16 + lr) * 32 + lq * 8];
#pragma unroll
    for (int j = 0; j < 4; ++j)
      bv[j] = *(const vs8*)&Bs[(wn * 64 + j * 16 + lr) * 32 + lq * 8];
#pragma unroll
    for (int i = 0; i < 4; ++i)
#pragma unroll
      for (int j = 0; j < 4; ++j)
        acc[i][j] = __builtin_amdgcn_mfma_f32_16x16x32_bf16(av[i], bv[j], acc[i][j], 0, 0, 0);
    __syncthreads();
  }

#pragma unroll
  for (int i = 0; i < 4; ++i) {
    int row0 = m0 + wm * 64 + i * 16 + lq * 4;
#pragma unroll
    for (int j = 0; j < 4; ++j) {
      int col = n0 + wn * 64 + j * 16 + lr;
      float bb = bias[col];
#pragma unroll
      for (int r = 0; r < 4; ++r) {
        size_t idx = (size_t)(row0 + r) * N + col;
        outB[idx] = __float2bfloat16(fmaxf(acc[i][j][r] + bb, 0.0f));
      }
    }
  }
}

// ---------------- bf16 MFMA GEMM 64x128 (qkv): C = A@W + bias -> f16 ----------------
__global__ __launch_bounds__(256, 2) void gemm_qkv(
    const u16* __restrict__ A, const u16* __restrict__ Bt,
    const float* __restrict__ bias, f16* __restrict__ outH,
    int M, int N, int K) {
  __shared__ u16 As[64 * 32];
  __shared__ u16 Bs[128 * 32];
  int tid = threadIdx.x;
  int wave = tid >> 6, lane = tid & 63;
  int wm = wave & 1, wn = wave >> 1;              // wave = 32 rows x 64 cols
  int m0 = blockIdx.y * 64, n0 = blockIdx.x * 128;
  int lr = lane & 15, lq = lane >> 4;

  vf4 acc[2][4];
#pragma unroll
  for (int i = 0; i < 2; ++i)
#pragma unroll
    for (int j = 0; j < 4; ++j) { acc[i][j][0]=0.f; acc[i][j][1]=0.f; acc[i][j][2]=0.f; acc[i][j][3]=0.f; }

  int sr = tid >> 2, sc = (tid & 3) * 8;
  const u16* ag = A + (size_t)(m0 + sr) * K + sc;
  const u16* bg = Bt + (size_t)(n0 + sr) * K + sc;
  u16* al = As + sr * 32 + sc;
  u16* bl = Bs + sr * 32 + sc;

  for (int k0 = 0; k0 < K; k0 += 32) {
    gload16(ag + k0, al);
    gload16(bg + k0, bl);
    gload16(bg + k0 + (size_t)64 * K, bl + 64 * 32);
    __syncthreads();
    vs8 av[2], bv[4];
#pragma unroll
    for (int i = 0; i < 2; ++i)
      av[i] = *(const vs8*)&As[(wm * 32 + i * 16 + lr) * 32 + lq * 8];
#pragma unroll
    for (int j = 0; j < 4; ++j)
      bv[j] = *(const vs8*)&Bs[(wn * 64 + j * 16 + lr) * 32 + lq * 8];
#pragma unroll
    for (int i = 0; i < 2; ++i)
#pragma unroll
      for (int j = 0; j < 4; ++j)
        acc[i][j] = __builtin_amdgcn_mfma_f32_16x16x32_bf16(av[i], bv[j], acc[i][j], 0, 0, 0);
    __syncthreads();
  }

#pragma unroll
  for (int i = 0; i < 2; ++i) {
    int row0 = m0 + wm * 32 + i * 16 + lq * 4;
#pragma unroll
    for (int j = 0; j < 4; ++j) {
      int col = n0 + wn * 64 + j * 16 + lr;
      float bb = bias[col];
#pragma unroll
      for (int r = 0; r < 4; ++r)
        outH[(size_t)(row0 + r) * N + col] = (f16)(acc[i][j][r] + bb);
    }
  }
}

// ---------------- fused GEMM (N=256) + bias + residual + LayerNorm, 32-row tiles ----------------
__global__ __launch_bounds__(256, 2) void gemm_ln(
    const u16* __restrict__ A, const u16* __restrict__ Bt,
    const float* __restrict__ bias, const float* __restrict__ res,
    const float* __restrict__ gam, const float* __restrict__ bet,
    float* __restrict__ outF, __hip_bfloat16* __restrict__ outB, int K) {
  __shared__ u16 As[32 * 32];
  __shared__ u16 Bs[256 * 32];
  __shared__ float ps[2][32], ps2[2][32], mur[32], rsr[32];
  int tid = threadIdx.x;
  int wave = tid >> 6, lane = tid & 63;
  int wm = wave & 1, wn = wave >> 1;
  int lr = lane & 15, lq = lane >> 4;
  int m0 = blockIdx.x * 32;

  vf4 acc[8];
#pragma unroll
  for (int j = 0; j < 8; ++j) { acc[j][0]=0.f; acc[j][1]=0.f; acc[j][2]=0.f; acc[j][3]=0.f; }

  int sr = tid >> 2, sc = (tid & 3) * 8;
  const u16* ag = A + (size_t)(m0 + sr) * K + sc;   // valid for tid<128 (rows 0..31)
  const u16* bg = Bt + (size_t)sr * K + sc;         // 256 rows: 4 rounds
  u16* al = As + sr * 32 + sc;
  u16* bl = Bs + sr * 32 + sc;

  for (int k0 = 0; k0 < K; k0 += 32) {
    if (tid < 128) gload16(ag + k0, al);
#pragma unroll
    for (int r = 0; r < 4; ++r)
      gload16(bg + k0 + (size_t)64 * r * K, bl + 64 * r * 32);
    __syncthreads();
    vs8 av, bv[8];
    av = *(const vs8*)&As[(wm * 16 + lr) * 32 + lq * 8];
#pragma unroll
    for (int j = 0; j < 8; ++j)
      bv[j] = *(const vs8*)&Bs[(wn * 128 + j * 16 + lr) * 32 + lq * 8];
#pragma unroll
    for (int j = 0; j < 8; ++j)
      acc[j] = __builtin_amdgcn_mfma_f32_16x16x32_bf16(av, bv[j], acc[j], 0, 0, 0);
    __syncthreads();
  }

  float sum_[4], sq_[4];
#pragma unroll
  for (int r = 0; r < 4; ++r) { sum_[r] = 0.f; sq_[r] = 0.f; }
#pragma unroll
  for (int j = 0; j < 8; ++j) {
    int col = wn * 128 + j * 16 + lr;
    float bb = bias[col];
#pragma unroll
    for (int r = 0; r < 4; ++r) {
      int row = m0 + wm * 16 + lq * 4 + r;
      float v = acc[j][r] + bb + res[(size_t)row * 256 + col];
      acc[j][r] = v;
      sum_[r] += v;
      sq_[r] += v * v;
    }
  }
#pragma unroll
  for (int r = 0; r < 4; ++r) {
#pragma unroll
    for (int m = 1; m <= 8; m <<= 1) {
      sum_[r] += __shfl_xor(sum_[r], m);
      sq_[r]  += __shfl_xor(sq_[r], m);
    }
  }
  if (lr == 0) {
#pragma unroll
    for (int r = 0; r < 4; ++r) {
      int rl = wm * 16 + lq * 4 + r;
      ps[wn][rl] = sum_[r];
      ps2[wn][rl] = sq_[r];
    }
  }
  __syncthreads();
  if (tid < 32) {
    float s = ps[0][tid] + ps[1][tid];
    float s2 = ps2[0][tid] + ps2[1][tid];
    float mu = s * (1.0f / 256.0f);
    float var = s2 * (1.0f / 256.0f) - mu * mu;
    mur[tid] = mu;
    rsr[tid] = rsqrtf(var + 1e-5f);
  }
  __syncthreads();
#pragma unroll
  for (int r = 0; r < 4; ++r) {
    int rl = wm * 16 + lq * 4 + r;
    float mu = mur[rl], rs = rsr[rl];
    int row = m0 + rl;
#pragma unroll
    for (int j = 0; j < 8; ++j) {
      int col = wn * 128 + j * 16 + lr;
      float o = (acc[j][r] - mu) * rs * gam[col] + bet[col];
      size_t idx = (size_t)row * 256 + col;
      outF[idx] = o;
      outB[idx] = __float2bfloat16(o);
    }
  }
}

// ---------------- MFMA flash attention v4: big q-tile, no kv-split ----------------
// qkv: [B*T][768] f16, col = h*96 + {0:q,32:k,64:v} + d.  out: [B*T][256] bf16, col=h*32+d.
// Block: 512 thr = 8 waves = 8 q-slices of 32 rows (q-tile 256). Grid (8,8,4) = 256 blocks.
// Each wave sweeps the FULL kv (32 chunks of 64 rows): no merge, no kv-split, l = ones-MFMA.
// Double-buffered LDS, ONE barrier per chunk: stage c+1 into buf^1 (waves 0-3: K via
// load->ds_write_b128 into pad-40 rows = 16B-aligned + 2-way-free banks; waves 4-7: V
// transposed into pad-68). Loads issue before compute, LDS writes after -> latency hidden.
__global__ __launch_bounds__(512, 4) void attn_mfma(const f16* __restrict__ qkv,
                                                    __hip_bfloat16* __restrict__ out) {
  // per buf: K [64][40] = 2560 u16, VT [32][68] = 2176 u16 -> 4736 u16; x2 bufs = 18944 B
  __shared__ __align__(16) u16 lds[2][4736];
  int tid = threadIdx.x;
  int wave = tid >> 6, lane = tid & 63;
  int lr = lane & 15, quad = lane >> 4;
  int h = blockIdx.y, b = blockIdx.z;
  int q0 = blockIdx.x * 256;
  int rowbase = b * 2048;
  const f16* base_bh = qkv + (size_t)rowbase * 768 + h * 96;

  // Q B-frags for this wave's 32 q rows, pre-scaled by (1/sqrt(32))*log2(e)
  vh8 qf[2];
#pragma unroll
  for (int nt = 0; nt < 2; ++nt) {
    int qr = q0 + wave * 32 + nt * 16 + lr;
    vh8 t = *(const vh8*)(base_bh + (size_t)qr * 768 + quad * 8);
#pragma unroll
    for (int j = 0; j < 8; ++j) t[j] = t[j] * (f16)0.25508682f;
    qf[nt] = t;
  }

  vf4 O[2][2], lO[2];
#pragma unroll
  for (int a = 0; a < 2; ++a) {
    lO[a][0]=0.f; lO[a][1]=0.f; lO[a][2]=0.f; lO[a][3]=0.f;
#pragma unroll
    for (int d = 0; d < 2; ++d) { O[a][d][0]=0.f; O[a][d][1]=0.f; O[a][d][2]=0.f; O[a][d][3]=0.f; }
  }

  // staging maps
  // waves 0-3 (256 lanes): K rows 0..63, 16B each: row = wave*16 + (lane>>2), col=(lane&3)*8
  int krow = wave * 16 + (lane >> 2);
  int kcol = (lane & 3) * 8;
  const f16* kg = base_bh + (size_t)krow * 768 + 32 + kcol;   // + c*64*768
  // waves 4-7 (256 lanes): V rows pair 2*kvp, 4 d each: kvp = t>>3 (0..31), d4=(t&7)*4
  int tv = tid & 255;
  int kvp = tv >> 3;
  int d4 = (tv & 7) * 4;
  const f16* vg = base_bh + (size_t)(kvp * 2) * 768 + 64 + d4;  // + c*64*768

  const vf4 z4 = {0.f, 0.f, 0.f, 0.f};
  const vh4 onesh = {(f16)1.0f, (f16)1.0f, (f16)1.0f, (f16)1.0f};
  const size_t cstep = (size_t)64 * 768;

  // ---- stage chunk 0 into buf 0 ----
  if (wave < 4) {
    vh8 k0 = *(const vh8*)kg;
    *(vh8*)&lds[0][krow * 40 + kcol] = k0;
  } else {
    vh4 a = *(const vh4*)vg;
    vh4 bb = *(const vh4*)(vg + 768);
#pragma unroll
    for (int i = 0; i < 4; ++i) {
      vh2 pr; pr[0] = a[i]; pr[1] = bb[i];
      *(vh2*)((f16*)&lds[0][2560] + (d4 + i) * 68 + kvp * 2) = pr;
    }
  }
  __syncthreads();

  for (int c = 0; c < 32; ++c) {
    int cur = c & 1;
    const f16* Ks = (const f16*)&lds[cur][0];
    const f16* VT = (const f16*)&lds[cur][2560];

    // issue next-chunk loads (complete during compute)
    vh8 kn; vh4 va, vb;
    if (c < 31) {
      if (wave < 4) {
        kn = *(const vh8*)(kg + (size_t)(c + 1) * cstep);
      } else {
        const f16* vp = vg + (size_t)(c + 1) * cstep;
        va = *(const vh4*)vp;
        vb = *(const vh4*)(vp + 768);
      }
    }

#pragma unroll
    for (int t16 = 0; t16 < 4; ++t16) {
      vh8 ak = *(const vh8*)&Ks[(t16 * 16 + lr) * 40 + quad * 8];
      vf4 s0 = __builtin_amdgcn_mfma_f32_16x16x32_f16(ak, qf[0], z4, 0, 0, 0);
      vf4 s1 = __builtin_amdgcn_mfma_f32_16x16x32_f16(ak, qf[1], z4, 0, 0, 0);
      vh4 p0, p1;
#pragma unroll
      for (int i = 0; i < 4; ++i) {
        p0[i] = (f16)exp2f(s0[i]);
        p1[i] = (f16)exp2f(s1[i]);
      }
      vh4 vf0 = *(const vh4*)&VT[(0 * 16 + lr) * 68 + t16 * 16 + quad * 4];
      vh4 vf1 = *(const vh4*)&VT[(1 * 16 + lr) * 68 + t16 * 16 + quad * 4];
      O[0][0] = __builtin_amdgcn_mfma_f32_16x16x16f16(p0, vf0, O[0][0], 0, 0, 0);
      O[0][1] = __builtin_amdgcn_mfma_f32_16x16x16f16(p0, vf1, O[0][1], 0, 0, 0);
      O[1][0] = __builtin_amdgcn_mfma_f32_16x16x16f16(p1, vf0, O[1][0], 0, 0, 0);
      O[1][1] = __builtin_amdgcn_mfma_f32_16x16x16f16(p1, vf1, O[1][1], 0, 0, 0);
      lO[0] = __builtin_amdgcn_mfma_f32_16x16x16f16(p0, onesh, lO[0], 0, 0, 0);
      lO[1] = __builtin_amdgcn_mfma_f32_16x16x16f16(p1, onesh, lO[1], 0, 0, 0);
    }

    // write next chunk into the other buffer (its old readers finished before last barrier)
    if (c < 31) {
      if (wave < 4) {
        *(vh8*)&lds[cur ^ 1][krow * 40 + kcol] = kn;
      } else {
#pragma unroll
        for (int i = 0; i < 4; ++i) {
          vh2 pr; pr[0] = va[i]; pr[1] = vb[i];
          *(vh2*)((f16*)&lds[cur ^ 1][2560] + (d4 + i) * 68 + kvp * 2) = pr;
        }
      }
    }
    __syncthreads();
  }

  // epilogue: l is lane-aligned with O (row q = quad*4+r for both)
#pragma unroll
  for (int nt = 0; nt < 2; ++nt) {
#pragma unroll
    for (int r = 0; r < 4; ++r) {
      float inv = 1.0f / lO[nt][r];
      int row = rowbase + q0 + wave * 32 + nt * 16 + quad * 4 + r;
#pragma unroll
      for (int dt = 0; dt < 2; ++dt) {
        int col = h * 32 + dt * 16 + lr;
        out[(size_t)row * 256 + col] = __float2bfloat16(O[nt][dt][r] * inv);
      }
    }
  }
}

// ---------------- driver ----------------
extern "C" void kernel_launch(void* const* d_in, const int* in_sizes, int n_in,
                              void* d_out, int out_size, void* d_ws, size_t ws_size,
                              hipStream_t stream) {
  (void)in_sizes; (void)n_in; (void)out_size; (void)ws_size;
  const float* x     = (const float*)d_in[0];
  const float* qkv_b = (const float*)d_in[2];
  const float* out_b = (const float*)d_in[4];
  const float* ff1_b = (const float*)d_in[6];
  const float* ff2_b = (const float*)d_in[8];
  const float* ln1_g = (const float*)d_in[9];
  const float* ln1_b = (const float*)d_in[10];
  const float* ln2_g = (const float*)d_in[11];
  const float* ln2_b = (const float*)d_in[12];

  // ws layout (bytes); total = 44,040,192
  char* ws = (char*)d_ws;
  float*          X     = (float*)(ws + 0);                    // 8192x256 f32
  __hip_bfloat16* Xb    = (__hip_bfloat16*)(ws + 8388608);     // bf16 x
  __hip_bfloat16* attnB = (__hip_bfloat16*)(ws + 20971520);    // attn out bf16 (4 MB)
  f16*            qkvH  = (f16*)(ws + 25165824);               // 8192x768 f16 (12.6 MB)
  __hip_bfloat16* hB    = (__hip_bfloat16*)(ws + 20971520);    // ff1 out bf16 (16.8 MB) overlaps attnB+qkvH
  u16* qkvwT = (u16*)(ws + 37748736);  // [L][768][256] bf16
  u16* outwT = (u16*)(ws + 39321600);  // [L][256][256]
  u16* ff1wT = (u16*)(ws + 39845888);  // [L][1024][256]
  u16* ff2wT = (u16*)(ws + 41943040);  // [L][256][1024]  ends 44,040,192

  pe_kernel<<<8192, 256, 0, stream>>>(x, X, Xb);
  transpose_cast<<<dim3(8, 24, 4), dim3(32, 8), 0, stream>>>((const float*)d_in[1], (__hip_bfloat16*)qkvwT, 256, 768);
  transpose_cast<<<dim3(8, 8, 4),  dim3(32, 8), 0, stream>>>((const float*)d_in[3], (__hip_bfloat16*)outwT, 256, 256);
  transpose_cast<<<dim3(8, 32, 4), dim3(32, 8), 0, stream>>>((const float*)d_in[5], (__hip_bfloat16*)ff1wT, 256, 1024);
  transpose_cast<<<dim3(32, 8, 4), dim3(32, 8), 0, stream>>>((const float*)d_in[7], (__hip_bfloat16*)ff2wT, 1024, 256);

  for (int l = 0; l < 4; ++l) {
    // qkv = x @ qkv_w + b -> f16
    gemm_qkv<<<dim3(6, 128), 256, 0, stream>>>((const u16*)Xb, qkvwT + (size_t)l * 768 * 256,
        qkv_b + l * 768, qkvH, 8192, 768, 256);
    // attn (q-tile 256, no kv-split)
    attn_mfma<<<dim3(8, 8, 4), 512, 0, stream>>>(qkvH, attnB);
    // X = LN1(attn @ out_w + b + X); Xb = bf16(X)
    gemm_ln<<<256, 256, 0, stream>>>((const u16*)attnB, outwT + (size_t)l * 256 * 256,
        out_b + l * 256, X, ln1_g + l * 256, ln1_b + l * 256, X, Xb, 256);
    // h = relu(x @ ff1_w + b) -> bf16
    gemm_bf16<<<dim3(8, 64), 256, 0, stream>>>((const u16*)Xb, ff1wT + (size_t)l * 1024 * 256,
        ff1_b + l * 1024, hB, 8192, 1024, 256);
    // X/out = LN2(h @ ff2_w + b + X); Xb = bf16(.)
    float* lnout = (l == 3) ? (float*)d_out : X;
    gemm_ln<<<256, 256, 0, stream>>>((const u16*)hB, ff2wT + (size_t)l * 256 * 1024,
        ff2_b + l * 256, X, ln2_g + l * 256, ln2_b + l * 256, lnout, Xb, 1024);
  }
}

// Round 7
// 508.865 us; speedup vs baseline: 1.5943x; 1.1349x over previous
//
#include <hip/hip_runtime.h>
#include <hip/hip_bf16.h>
#include <stdint.h>

typedef unsigned short u16;
typedef _Float16 f16;
typedef short vs8 __attribute__((ext_vector_type(8)));   // 8 x bf16 bits (MFMA A/B frag)
typedef float vf4 __attribute__((ext_vector_type(4)));   // MFMA C/D frag
typedef _Float16 vh2 __attribute__((ext_vector_type(2)));
typedef _Float16 vh4 __attribute__((ext_vector_type(4)));
typedef _Float16 vh8 __attribute__((ext_vector_type(8)));
typedef __fp16 hw2 __attribute__((ext_vector_type(2)));  // cvt_pkrtz return type

// Problem constants: B=4 T=2048 E=256 H=8 HD=32 FE=4 L=4

__device__ __forceinline__ void gload16(const u16* g, u16* l) {
  __builtin_amdgcn_global_load_lds((const __attribute__((address_space(1))) void*)g,
                                   (__attribute__((address_space(3))) void*)l,
                                   16, 0, 0);
}

// raw v_exp_f32 (libm exp2f drags in range-fixup code: ~8 VALU instrs vs 1)
__device__ __forceinline__ float fexp2(float x) {
#if __has_builtin(__builtin_amdgcn_exp2f)
  return __builtin_amdgcn_exp2f(x);
#else
  return __expf(x * 0.69314718056f);
#endif
}

// ---------------- Fourier PE + bf16 cast ----------------
__global__ void pe_kernel(const float* __restrict__ x, float* __restrict__ X,
                          __hip_bfloat16* __restrict__ Xb) {
  int row = blockIdx.x;            // b*2048 + t
  int e = threadIdx.x;             // 0..255
  int t = row & 2047;
  int f = (e < 128) ? e : (e - 128);
  float freq = powf(10000.0f, -(float)f * (1.0f / 128.0f));
  float arg = (float)t * freq;
  float pe = (e < 128) ? sinf(arg) : cosf(arg);
  size_t idx = (size_t)row * 256 + e;
  float v = x[idx] + pe;
  X[idx] = v;
  Xb[idx] = __float2bfloat16(v);
}

// ---------------- weight transpose + cast: in[L][K][N] f32 -> out[L][N][K] bf16 ----------------
__global__ void transpose_cast(const float* __restrict__ in, __hip_bfloat16* __restrict__ out,
                               int K, int N) {
  __shared__ float tile[32][33];
  int layer = blockIdx.z;
  int k0 = blockIdx.x * 32, n0 = blockIdx.y * 32;
  const float* ip = in + (size_t)layer * K * N;
  __hip_bfloat16* op = out + (size_t)layer * N * K;
  int tx = threadIdx.x, ty = threadIdx.y;   // (32,8)
#pragma unroll
  for (int r = 0; r < 4; ++r) {
    int k = ty + r * 8;
    tile[k][tx] = ip[(size_t)(k0 + k) * N + (n0 + tx)];
  }
  __syncthreads();
#pragma unroll
  for (int r = 0; r < 4; ++r) {
    int n = ty + r * 8;
    op[(size_t)(n0 + n) * K + (k0 + tx)] = __float2bfloat16(tile[tx][n]);
  }
}

// ---------------- bf16 MFMA GEMM 128x128 (ff1): C = A@W + bias + relu -> bf16 ----------------
__global__ __launch_bounds__(256, 2) void gemm_bf16(
    const u16* __restrict__ A, const u16* __restrict__ Bt,
    const float* __restrict__ bias, __hip_bfloat16* __restrict__ outB,
    int M, int N, int K) {
  __shared__ u16 As[128 * 32];
  __shared__ u16 Bs[128 * 32];
  int tid = threadIdx.x;
  int wave = tid >> 6, lane = tid & 63;
  int wm = wave & 1, wn = wave >> 1;              // 2x2 waves of 64x64
  int m0 = blockIdx.y * 128, n0 = blockIdx.x * 128;
  int lr = lane & 15, lq = lane >> 4;

  vf4 acc[4][4];
#pragma unroll
  for (int i = 0; i < 4; ++i)
#pragma unroll
    for (int j = 0; j < 4; ++j) {
      acc[i][j][0] = 0.f; acc[i][j][1] = 0.f; acc[i][j][2] = 0.f; acc[i][j][3] = 0.f;
    }

  int srow = wave * 16 + (lane >> 2);
  int scol = (lane & 3) * 8;
  const u16* ag = A + (size_t)(m0 + srow) * K + scol;
  const u16* bg = Bt + (size_t)(n0 + srow) * K + scol;
  u16* al = As + srow * 32 + scol;
  u16* bl = Bs + srow * 32 + scol;
  const size_t rstride = (size_t)64 * K;

  for (int k0 = 0; k0 < K; k0 += 32) {
    gload16(ag + k0, al);
    gload16(ag + k0 + rstride, al + 64 * 32);
    gload16(bg + k0, bl);
    gload16(bg + k0 + rstride, bl + 64 * 32);
    __syncthreads();
    vs8 av[4], bv[4];
#pragma unroll
    for (int i = 0; i < 4; ++i)
      av[i] = *(const vs8*)&As[(wm * 64 + i * 16 + lr) * 32 + lq * 8];
#pragma unroll
    for (int j = 0; j < 4; ++j)
      bv[j] = *(const vs8*)&Bs[(wn * 64 + j * 16 + lr) * 32 + lq * 8];
#pragma unroll
    for (int i = 0; i < 4; ++i)
#pragma unroll
      for (int j = 0; j < 4; ++j)
        acc[i][j] = __builtin_amdgcn_mfma_f32_16x16x32_bf16(av[i], bv[j], acc[i][j], 0, 0, 0);
    __syncthreads();
  }

#pragma unroll
  for (int i = 0; i < 4; ++i) {
    int row0 = m0 + wm * 64 + i * 16 + lq * 4;
#pragma unroll
    for (int j = 0; j < 4; ++j) {
      int col = n0 + wn * 64 + j * 16 + lr;
      float bb = bias[col];
#pragma unroll
      for (int r = 0; r < 4; ++r) {
        size_t idx = (size_t)(row0 + r) * N + col;
        outB[idx] = __float2bfloat16(fmaxf(acc[i][j][r] + bb, 0.0f));
      }
    }
  }
}

// ---------------- bf16 MFMA GEMM 64x128 (qkv): C = A@W + bias -> f16 ----------------
__global__ __launch_bounds__(256, 2) void gemm_qkv(
    const u16* __restrict__ A, const u16* __restrict__ Bt,
    const float* __restrict__ bias, f16* __restrict__ outH,
    int M, int N, int K) {
  __shared__ u16 As[64 * 32];
  __shared__ u16 Bs[128 * 32];
  int tid = threadIdx.x;
  int wave = tid >> 6, lane = tid & 63;
  int wm = wave & 1, wn = wave >> 1;              // wave = 32 rows x 64 cols
  int m0 = blockIdx.y * 64, n0 = blockIdx.x * 128;
  int lr = lane & 15, lq = lane >> 4;

  vf4 acc[2][4];
#pragma unroll
  for (int i = 0; i < 2; ++i)
#pragma unroll
    for (int j = 0; j < 4; ++j) { acc[i][j][0]=0.f; acc[i][j][1]=0.f; acc[i][j][2]=0.f; acc[i][j][3]=0.f; }

  int sr = tid >> 2, sc = (tid & 3) * 8;
  const u16* ag = A + (size_t)(m0 + sr) * K + sc;
  const u16* bg = Bt + (size_t)(n0 + sr) * K + sc;
  u16* al = As + sr * 32 + sc;
  u16* bl = Bs + sr * 32 + sc;

  for (int k0 = 0; k0 < K; k0 += 32) {
    gload16(ag + k0, al);
    gload16(bg + k0, bl);
    gload16(bg + k0 + (size_t)64 * K, bl + 64 * 32);
    __syncthreads();
    vs8 av[2], bv[4];
#pragma unroll
    for (int i = 0; i < 2; ++i)
      av[i] = *(const vs8*)&As[(wm * 32 + i * 16 + lr) * 32 + lq * 8];
#pragma unroll
    for (int j = 0; j < 4; ++j)
      bv[j] = *(const vs8*)&Bs[(wn * 64 + j * 16 + lr) * 32 + lq * 8];
#pragma unroll
    for (int i = 0; i < 2; ++i)
#pragma unroll
      for (int j = 0; j < 4; ++j)
        acc[i][j] = __builtin_amdgcn_mfma_f32_16x16x32_bf16(av[i], bv[j], acc[i][j], 0, 0, 0);
    __syncthreads();
  }

#pragma unroll
  for (int i = 0; i < 2; ++i) {
    int row0 = m0 + wm * 32 + i * 16 + lq * 4;
#pragma unroll
    for (int j = 0; j < 4; ++j) {
      int col = n0 + wn * 64 + j * 16 + lr;
      float bb = bias[col];
#pragma unroll
      for (int r = 0; r < 4; ++r)
        outH[(size_t)(row0 + r) * N + col] = (f16)(acc[i][j][r] + bb);
    }
  }
}

// ---------------- fused GEMM (N=256) + bias + residual + LayerNorm, 32-row tiles ----------------
__global__ __launch_bounds__(256, 2) void gemm_ln(
    const u16* __restrict__ A, const u16* __restrict__ Bt,
    const float* __restrict__ bias, const float* __restrict__ res,
    const float* __restrict__ gam, const float* __restrict__ bet,
    float* __restrict__ outF, __hip_bfloat16* __restrict__ outB, int K) {
  __shared__ u16 As[32 * 32];
  __shared__ u16 Bs[256 * 32];
  __shared__ float ps[2][32], ps2[2][32], mur[32], rsr[32];
  int tid = threadIdx.x;
  int wave = tid >> 6, lane = tid & 63;
  int wm = wave & 1, wn = wave >> 1;
  int lr = lane & 15, lq = lane >> 4;
  int m0 = blockIdx.x * 32;

  vf4 acc[8];
#pragma unroll
  for (int j = 0; j < 8; ++j) { acc[j][0]=0.f; acc[j][1]=0.f; acc[j][2]=0.f; acc[j][3]=0.f; }

  int sr = tid >> 2, sc = (tid & 3) * 8;
  const u16* ag = A + (size_t)(m0 + sr) * K + sc;   // valid for tid<128 (rows 0..31)
  const u16* bg = Bt + (size_t)sr * K + sc;         // 256 rows: 4 rounds
  u16* al = As + sr * 32 + sc;
  u16* bl = Bs + sr * 32 + sc;

  for (int k0 = 0; k0 < K; k0 += 32) {
    if (tid < 128) gload16(ag + k0, al);
#pragma unroll
    for (int r = 0; r < 4; ++r)
      gload16(bg + k0 + (size_t)64 * r * K, bl + 64 * r * 32);
    __syncthreads();
    vs8 av, bv[8];
    av = *(const vs8*)&As[(wm * 16 + lr) * 32 + lq * 8];
#pragma unroll
    for (int j = 0; j < 8; ++j)
      bv[j] = *(const vs8*)&Bs[(wn * 128 + j * 16 + lr) * 32 + lq * 8];
#pragma unroll
    for (int j = 0; j < 8; ++j)
      acc[j] = __builtin_amdgcn_mfma_f32_16x16x32_bf16(av, bv[j], acc[j], 0, 0, 0);
    __syncthreads();
  }

  float sum_[4], sq_[4];
#pragma unroll
  for (int r = 0; r < 4; ++r) { sum_[r] = 0.f; sq_[r] = 0.f; }
#pragma unroll
  for (int j = 0; j < 8; ++j) {
    int col = wn * 128 + j * 16 + lr;
    float bb = bias[col];
#pragma unroll
    for (int r = 0; r < 4; ++r) {
      int row = m0 + wm * 16 + lq * 4 + r;
      float v = acc[j][r] + bb + res[(size_t)row * 256 + col];
      acc[j][r] = v;
      sum_[r] += v;
      sq_[r] += v * v;
    }
  }
#pragma unroll
  for (int r = 0; r < 4; ++r) {
#pragma unroll
    for (int m = 1; m <= 8; m <<= 1) {
      sum_[r] += __shfl_xor(sum_[r], m);
      sq_[r]  += __shfl_xor(sq_[r], m);
    }
  }
  if (lr == 0) {
#pragma unroll
    for (int r = 0; r < 4; ++r) {
      int rl = wm * 16 + lq * 4 + r;
      ps[wn][rl] = sum_[r];
      ps2[wn][rl] = sq_[r];
    }
  }
  __syncthreads();
  if (tid < 32) {
    float s = ps[0][tid] + ps[1][tid];
    float s2 = ps2[0][tid] + ps2[1][tid];
    float mu = s * (1.0f / 256.0f);
    float var = s2 * (1.0f / 256.0f) - mu * mu;
    mur[tid] = mu;
    rsr[tid] = rsqrtf(var + 1e-5f);
  }
  __syncthreads();
#pragma unroll
  for (int r = 0; r < 4; ++r) {
    int rl = wm * 16 + lq * 4 + r;
    float mu = mur[rl], rs = rsr[rl];
    int row = m0 + rl;
#pragma unroll
    for (int j = 0; j < 8; ++j) {
      int col = wn * 128 + j * 16 + lr;
      float o = (acc[j][r] - mu) * rs * gam[col] + bet[col];
      size_t idx = (size_t)row * 256 + col;
      outF[idx] = o;
      outB[idx] = __float2bfloat16(o);
    }
  }
}

// ---------------- MFMA flash attention v5: v4 structure + raw exp + pk-cvt + XCD pin ----------------
// Block: 512 thr = 8 waves = 8 q-slices of 32 rows (q-tile 256). Grid 256 (1D, XCD-pinned:
// xcd=id&7 owns 4 (b,h) groups -> ~1 MB K/V L2-resident per XCD; R5-proven FETCH 51->8 MB).
// Hot loop exp path: __builtin_amdgcn_exp2f (1 instr) + cvt_pkrtz (2 vals/instr): ~12 VALU
// per t16 vs ~70 with libm exp2f — attacks the measured 53% VALUBusy at MfmaUtil 23%.
__global__ __launch_bounds__(512, 4) void attn_mfma(const f16* __restrict__ qkv,
                                                    __hip_bfloat16* __restrict__ out) {
  // per buf: K [64][40] = 2560 u16, VT [32][68] = 2176 u16 -> 4736 u16; x2 bufs = 18944 B
  __shared__ __align__(16) u16 lds[2][4736];
  int tid = threadIdx.x;
  int wave = tid >> 6, lane = tid & 63;
  int lr = lane & 15, quad = lane >> 4;

  // XCD pin: linear id round-robins across 8 XCDs (id&7). 32 blocks/XCD = 4 (b,h) x 8 q-tiles.
  int id = blockIdx.x;
  int xcd = id & 7, slot = id >> 3;
  int grp = xcd * 4 + (slot & 3);             // (b,h) group 0..31, 4 per XCD
  int qt = slot >> 2;                          // q-tile 0..7
  int b = grp >> 3, h = grp & 7;
  int q0 = qt * 256;
  int rowbase = b * 2048;
  const f16* base_bh = qkv + (size_t)rowbase * 768 + h * 96;

  // Q B-frags for this wave's 32 q rows, pre-scaled by (1/sqrt(32))*log2(e)
  vh8 qf[2];
#pragma unroll
  for (int nt = 0; nt < 2; ++nt) {
    int qr = q0 + wave * 32 + nt * 16 + lr;
    vh8 t = *(const vh8*)(base_bh + (size_t)qr * 768 + quad * 8);
#pragma unroll
    for (int j = 0; j < 8; ++j) t[j] = t[j] * (f16)0.25508682f;
    qf[nt] = t;
  }

  vf4 O[2][2], lO[2];
#pragma unroll
  for (int a = 0; a < 2; ++a) {
    lO[a][0]=0.f; lO[a][1]=0.f; lO[a][2]=0.f; lO[a][3]=0.f;
#pragma unroll
    for (int d = 0; d < 2; ++d) { O[a][d][0]=0.f; O[a][d][1]=0.f; O[a][d][2]=0.f; O[a][d][3]=0.f; }
  }

  // staging maps: waves 0-3 stage K, waves 4-7 stage V (transposed)
  int krow = wave * 16 + (lane >> 2);
  int kcol = (lane & 3) * 8;
  const f16* kg = base_bh + (size_t)krow * 768 + 32 + kcol;
  int tv = tid & 255;
  int kvp = tv >> 3;
  int d4 = (tv & 7) * 4;
  const f16* vg = base_bh + (size_t)(kvp * 2) * 768 + 64 + d4;

  const vf4 z4 = {0.f, 0.f, 0.f, 0.f};
  const vh4 onesh = {(f16)1.0f, (f16)1.0f, (f16)1.0f, (f16)1.0f};
  const size_t cstep = (size_t)64 * 768;

  // ---- stage chunk 0 into buf 0 ----
  if (wave < 4) {
    vh8 k0 = *(const vh8*)kg;
    *(vh8*)&lds[0][krow * 40 + kcol] = k0;
  } else {
    vh4 a = *(const vh4*)vg;
    vh4 bb = *(const vh4*)(vg + 768);
#pragma unroll
    for (int i = 0; i < 4; ++i) {
      vh2 pr; pr[0] = a[i]; pr[1] = bb[i];
      *(vh2*)((f16*)&lds[0][2560] + (d4 + i) * 68 + kvp * 2) = pr;
    }
  }
  __syncthreads();

  for (int c = 0; c < 32; ++c) {
    int cur = c & 1;
    const f16* Ks = (const f16*)&lds[cur][0];
    const f16* VT = (const f16*)&lds[cur][2560];

    // issue next-chunk loads (complete during compute)
    vh8 kn; vh4 va, vb;
    if (c < 31) {
      if (wave < 4) {
        kn = *(const vh8*)(kg + (size_t)(c + 1) * cstep);
      } else {
        const f16* vp = vg + (size_t)(c + 1) * cstep;
        va = *(const vh4*)vp;
        vb = *(const vh4*)(vp + 768);
      }
    }

#pragma unroll
    for (int t16 = 0; t16 < 4; ++t16) {
      vh8 ak = *(const vh8*)&Ks[(t16 * 16 + lr) * 40 + quad * 8];
      vf4 s0 = __builtin_amdgcn_mfma_f32_16x16x32_f16(ak, qf[0], z4, 0, 0, 0);
      vf4 s1 = __builtin_amdgcn_mfma_f32_16x16x32_f16(ak, qf[1], z4, 0, 0, 0);
      vh4 p0, p1;
      ((hw2*)&p0)[0] = __builtin_amdgcn_cvt_pkrtz(fexp2(s0[0]), fexp2(s0[1]));
      ((hw2*)&p0)[1] = __builtin_amdgcn_cvt_pkrtz(fexp2(s0[2]), fexp2(s0[3]));
      ((hw2*)&p1)[0] = __builtin_amdgcn_cvt_pkrtz(fexp2(s1[0]), fexp2(s1[1]));
      ((hw2*)&p1)[1] = __builtin_amdgcn_cvt_pkrtz(fexp2(s1[2]), fexp2(s1[3]));
      vh4 vf0 = *(const vh4*)&VT[(0 * 16 + lr) * 68 + t16 * 16 + quad * 4];
      vh4 vf1 = *(const vh4*)&VT[(1 * 16 + lr) * 68 + t16 * 16 + quad * 4];
      O[0][0] = __builtin_amdgcn_mfma_f32_16x16x16f16(p0, vf0, O[0][0], 0, 0, 0);
      O[0][1] = __builtin_amdgcn_mfma_f32_16x16x16f16(p0, vf1, O[0][1], 0, 0, 0);
      O[1][0] = __builtin_amdgcn_mfma_f32_16x16x16f16(p1, vf0, O[1][0], 0, 0, 0);
      O[1][1] = __builtin_amdgcn_mfma_f32_16x16x16f16(p1, vf1, O[1][1], 0, 0, 0);
      lO[0] = __builtin_amdgcn_mfma_f32_16x16x16f16(p0, onesh, lO[0], 0, 0, 0);
      lO[1] = __builtin_amdgcn_mfma_f32_16x16x16f16(p1, onesh, lO[1], 0, 0, 0);
    }

    // write next chunk into the other buffer
    if (c < 31) {
      if (wave < 4) {
        *(vh8*)&lds[cur ^ 1][krow * 40 + kcol] = kn;
      } else {
#pragma unroll
        for (int i = 0; i < 4; ++i) {
          vh2 pr; pr[0] = va[i]; pr[1] = vb[i];
          *(vh2*)((f16*)&lds[cur ^ 1][2560] + (d4 + i) * 68 + kvp * 2) = pr;
        }
      }
    }
    __syncthreads();
  }

  // epilogue: l is lane-aligned with O (row q = quad*4+r for both)
#pragma unroll
  for (int nt = 0; nt < 2; ++nt) {
#pragma unroll
    for (int r = 0; r < 4; ++r) {
      float inv = 1.0f / lO[nt][r];
      int row = rowbase + q0 + wave * 32 + nt * 16 + quad * 4 + r;
#pragma unroll
      for (int dt = 0; dt < 2; ++dt) {
        int col = h * 32 + dt * 16 + lr;
        out[(size_t)row * 256 + col] = __float2bfloat16(O[nt][dt][r] * inv);
      }
    }
  }
}

// ---------------- driver ----------------
extern "C" void kernel_launch(void* const* d_in, const int* in_sizes, int n_in,
                              void* d_out, int out_size, void* d_ws, size_t ws_size,
                              hipStream_t stream) {
  (void)in_sizes; (void)n_in; (void)out_size; (void)ws_size;
  const float* x     = (const float*)d_in[0];
  const float* qkv_b = (const float*)d_in[2];
  const float* out_b = (const float*)d_in[4];
  const float* ff1_b = (const float*)d_in[6];
  const float* ff2_b = (const float*)d_in[8];
  const float* ln1_g = (const float*)d_in[9];
  const float* ln1_b = (const float*)d_in[10];
  const float* ln2_g = (const float*)d_in[11];
  const float* ln2_b = (const float*)d_in[12];

  // ws layout (bytes); total = 44,040,192
  char* ws = (char*)d_ws;
  float*          X     = (float*)(ws + 0);                    // 8192x256 f32
  __hip_bfloat16* Xb    = (__hip_bfloat16*)(ws + 8388608);     // bf16 x
  __hip_bfloat16* attnB = (__hip_bfloat16*)(ws + 20971520);    // attn out bf16 (4 MB)
  f16*            qkvH  = (f16*)(ws + 25165824);               // 8192x768 f16 (12.6 MB)
  __hip_bfloat16* hB    = (__hip_bfloat16*)(ws + 20971520);    // ff1 out bf16 (16.8 MB) overlaps attnB+qkvH
  u16* qkvwT = (u16*)(ws + 37748736);  // [L][768][256] bf16
  u16* outwT = (u16*)(ws + 39321600);  // [L][256][256]
  u16* ff1wT = (u16*)(ws + 39845888);  // [L][1024][256]
  u16* ff2wT = (u16*)(ws + 41943040);  // [L][256][1024]  ends 44,040,192

  pe_kernel<<<8192, 256, 0, stream>>>(x, X, Xb);
  transpose_cast<<<dim3(8, 24, 4), dim3(32, 8), 0, stream>>>((const float*)d_in[1], (__hip_bfloat16*)qkvwT, 256, 768);
  transpose_cast<<<dim3(8, 8, 4),  dim3(32, 8), 0, stream>>>((const float*)d_in[3], (__hip_bfloat16*)outwT, 256, 256);
  transpose_cast<<<dim3(8, 32, 4), dim3(32, 8), 0, stream>>>((const float*)d_in[5], (__hip_bfloat16*)ff1wT, 256, 1024);
  transpose_cast<<<dim3(32, 8, 4), dim3(32, 8), 0, stream>>>((const float*)d_in[7], (__hip_bfloat16*)ff2wT, 1024, 256);

  for (int l = 0; l < 4; ++l) {
    // qkv = x @ qkv_w + b -> f16
    gemm_qkv<<<dim3(6, 128), 256, 0, stream>>>((const u16*)Xb, qkvwT + (size_t)l * 768 * 256,
        qkv_b + l * 768, qkvH, 8192, 768, 256);
    // attn (q-tile 256, XCD-pinned 1D grid)
    attn_mfma<<<256, 512, 0, stream>>>(qkvH, attnB);
    // X = LN1(attn @ out_w + b + X); Xb = bf16(X)
    gemm_ln<<<256, 256, 0, stream>>>((const u16*)attnB, outwT + (size_t)l * 256 * 256,
        out_b + l * 256, X, ln1_g + l * 256, ln1_b + l * 256, X, Xb, 256);
    // h = relu(x @ ff1_w + b) -> bf16
    gemm_bf16<<<dim3(8, 64), 256, 0, stream>>>((const u16*)Xb, ff1wT + (size_t)l * 1024 * 256,
        ff1_b + l * 1024, hB, 8192, 1024, 256);
    // X/out = LN2(h @ ff2_w + b + X); Xb = bf16(.)
    float* lnout = (l == 3) ? (float*)d_out : X;
    gemm_ln<<<256, 256, 0, stream>>>((const u16*)hB, ff2wT + (size_t)l * 256 * 1024,
        ff2_b + l * 256, X, ln2_g + l * 256, ln2_b + l * 256, lnout, Xb, 1024);
  }
}